// Round 31
// baseline (1427.734 us; speedup 1.0000x reference)
//
#include <hip/hip_runtime.h>
#include <hip/hip_bf16.h>
#include <stdint.h>

#define BM 128
#define BN 128
#define BK 64
#define THREADS 256

typedef __attribute__((ext_vector_type(4))) float f32x4;
typedef __attribute__((ext_vector_type(8))) short bf16x8;
typedef __attribute__((ext_vector_type(4))) int i32x4;
typedef __attribute__((ext_vector_type(4))) unsigned int u32x4;

static __device__ __forceinline__ ushort f2bf(float f) {
    __hip_bfloat16 h = __float2bfloat16(f);   // RNE
    return *(const ushort*)&h;
}

// Round 31: THE OUTPUT IS FLOAT32. d_out = f32[4*2048*11008] (360 MB).
// 30-round root cause: I assumed bf16 output from the checker's `u<<16`
// branch; the actual dtype hits the `else: np.float32` branch. All ushort
// writes were being read as f32 words (hi<<16|lo) — every "shift/interleave/
// permutation" was an artifact. r30 inadvertently VALIDATED the full engine:
// its odd-ushort writes = f32 stores of tokens 0..4095, and absmax fell to
// exactly max|ref| over the unwritten second half (15.3125) — i.e. the
// written half MATCHED. np ref = posted formula: row-major, all 8192 tokens,
// posted decode (low nibble -> even k), per-channel scale, no shift.
__global__ __launch_bounds__(THREADS) void w4a16_gemm(
    const float* __restrict__ X,     // f32 [8192, K]
    const int*   __restrict__ WP,    // [N, K/2] packed nibbles (one byte per int32)
    const float* __restrict__ WS,    // f32 [N]
    float*       __restrict__ OUT,   // f32 [M, N]
    int M, int N, int K)
{
    __shared__ ushort Alds[BM][BK];
    __shared__ ushort Blds[BN][BK];

    const int tid  = threadIdx.x;
    const int wave = tid >> 6;
    const int lane = tid & 63;
    const int m0 = blockIdx.y * BM;
    const int n0 = blockIdx.x * BN;
    const int wr = wave >> 1;
    const int wc = wave & 1;

    f32x4 acc[4][4] = {};
    const int Khalf = K >> 1;

    for (int k0 = 0; k0 < K; k0 += BK) {
        // ---- A tile: f32 -> bf16 (RNE), 32B/thread loads ----
        #pragma unroll
        for (int i = 0; i < 4; ++i) {
            const int g   = i * THREADS + tid;
            const int row = g >> 3;
            const int col = (g & 7) * 8;
            const float* src = X + (size_t)(m0 + row) * K + (k0 + col);
            const f32x4 a0 = *(const f32x4*)(src);
            const f32x4 a1 = *(const f32x4*)(src + 4);
            u32x4 wv;
            wv[0] = ((uint)f2bf(a0[1]) << 16) | f2bf(a0[0]);
            wv[1] = ((uint)f2bf(a0[3]) << 16) | f2bf(a0[2]);
            wv[2] = ((uint)f2bf(a1[1]) << 16) | f2bf(a1[0]);
            wv[3] = ((uint)f2bf(a1[3]) << 16) | f2bf(a1[2]);
            *(u32x4*)&Alds[row][col] = wv;
        }
        // ---- B tile: posted decode (low nibble -> even k, high -> odd k) ----
        #pragma unroll
        for (int i = 0; i < 4; ++i) {
            const int g   = i * THREADS + tid;
            const int row = g >> 3;
            const int c4  = (g & 7) * 4;
            const i32x4 v = *(const i32x4*)(WP + (size_t)(n0 + row) * Khalf + (k0 >> 1) + c4);
            u32x4 wv;
            #pragma unroll
            for (int j = 0; j < 4; ++j) {
                const int b  = v[j];
                const int lo = (b << 28) >> 28;
                const int hi = (b << 24) >> 28;
                const unsigned flo = __builtin_bit_cast(unsigned, (float)lo);
                const unsigned fhi = __builtin_bit_cast(unsigned, (float)hi);
                wv[j] = (fhi & 0xFFFF0000u) | (flo >> 16);  // exact bf16 for [-8,7]
            }
            *(u32x4*)&Blds[row][c4 * 2] = wv;
        }
        __syncthreads();

        // ---- MFMA: 4 waves x 64x64, K=64 in 2 sub-steps ----
        #pragma unroll
        for (int kk = 0; kk < 2; ++kk) {
            bf16x8 af[4], bfr[4];
            #pragma unroll
            for (int i = 0; i < 4; ++i)
                af[i] = *(const bf16x8*)&Alds[wr * 64 + i * 16 + (lane & 15)][kk * 32 + (lane >> 4) * 8];
            #pragma unroll
            for (int i = 0; i < 4; ++i)
                bfr[i] = *(const bf16x8*)&Blds[wc * 64 + i * 16 + (lane & 15)][kk * 32 + (lane >> 4) * 8];
            #pragma unroll
            for (int mi = 0; mi < 4; ++mi)
                #pragma unroll
                for (int ni = 0; ni < 4; ++ni)
                    acc[mi][ni] = __builtin_amdgcn_mfma_f32_16x16x32_bf16(
                        af[mi], bfr[ni], acc[mi][ni], 0, 0, 0);
        }
        __syncthreads();
    }

    // ---- epilogue: per-channel scale, PLAIN F32 stores ----
    // C/D layout: col = lane&15, row = (lane>>4)*4 + r  [m89/m91; validated
    // end-to-end on 45M cells by r30's matched half]
    const int col_l = lane & 15;
    const int row_l = (lane >> 4) * 4;
    #pragma unroll
    for (int ni = 0; ni < 4; ++ni) {
        const int col = n0 + wc * 64 + ni * 16 + col_l;
        const float s = WS[col];
        #pragma unroll
        for (int mi = 0; mi < 4; ++mi) {
            const int row = m0 + wr * 64 + mi * 16 + row_l;
            #pragma unroll
            for (int r = 0; r < 4; ++r)
                OUT[(size_t)(row + r) * N + col] = acc[mi][ni][r] * s;
        }
    }
}

extern "C" void kernel_launch(void* const* d_in, const int* in_sizes, int n_in,
                              void* d_out, int out_size, void* d_ws, size_t ws_size,
                              hipStream_t stream) {
    const float* X  = (const float*)d_in[0];
    const int*   WP = (const int*)d_in[1];
    const float* WS = (const float*)d_in[2];
    float*       OUT = (float*)d_out;

    const int N     = in_sizes[2];          // 11008
    const int Khalf = in_sizes[1] / N;      // 2048
    const int K     = Khalf * 2;            // 4096
    const int M     = in_sizes[0] / K;      // 8192

    dim3 grid(N / BN, M / BM);              // (86, 64)
    w4a16_gemm<<<grid, dim3(THREADS), 0, stream>>>(X, WP, WS, OUT, M, N, K);
}

// Round 32
// 1222.679 us; speedup vs baseline: 1.1677x; 1.1677x over previous
//
#include <hip/hip_runtime.h>
#include <hip/hip_bf16.h>
#include <stdint.h>

#define BM 128
#define BN 128
#define BK 64
#define THREADS 256

typedef __attribute__((ext_vector_type(4))) float f32x4;
typedef __attribute__((ext_vector_type(8))) short bf16x8;
typedef __attribute__((ext_vector_type(4))) int i32x4;
typedef __attribute__((ext_vector_type(4))) unsigned int u32x4;

static __device__ __forceinline__ ushort f2bf(float f) {
    __hip_bfloat16 h = __float2bfloat16(f);   // RNE
    return *(const ushort*)&h;
}

// Round 32: hoist all dtype conversion out of the GEMM main loop.
// r31 counters: MfmaUtil 21%, VALUBusy 49% -> VALU-staging-bound. B-dequant
// (~256 cyc/wave/K-step > 160 cyc MFMA) was redone by all 64 M-blocks.
// Fix: (1) X f32->bf16 pre-pass into d_ws; (2) W nibble->bf16 [N,K] pre-pass
// into d_ws (once, not 64x); (3) main GEMM = pure bf16 m97-structure, BOTH
// operands staged via global_load_lds width=16 (r0===r2 bit-identity proved
// this path correct). Fallback to r31's in-loop-conversion kernel if d_ws
// is too small. Numerics bit-identical to r31 (absmax 0.0625 expected).

// ---- pre-pass 1: X f32 -> bf16 (8 elems/thread/iter) ----
__global__ __launch_bounds__(256) void cvt_x(
    const float* __restrict__ X, ushort* __restrict__ Xb, size_t n8)
{
    size_t i = (size_t)blockIdx.x * blockDim.x + threadIdx.x;
    const size_t stride = (size_t)gridDim.x * blockDim.x;
    for (; i < n8; i += stride) {
        const f32x4 a0 = *(const f32x4*)(X + i * 8);
        const f32x4 a1 = *(const f32x4*)(X + i * 8 + 4);
        u32x4 wv;
        wv[0] = ((uint)f2bf(a0[1]) << 16) | f2bf(a0[0]);
        wv[1] = ((uint)f2bf(a0[3]) << 16) | f2bf(a0[2]);
        wv[2] = ((uint)f2bf(a1[1]) << 16) | f2bf(a1[0]);
        wv[3] = ((uint)f2bf(a1[3]) << 16) | f2bf(a1[2]);
        *(u32x4*)(Xb + i * 8) = wv;
    }
}

// ---- pre-pass 2: W packed-nibble -> bf16 [N,K] (4 int32 -> 8 bf16/thread/iter) ----
__global__ __launch_bounds__(256) void cvt_w(
    const int* __restrict__ WP, ushort* __restrict__ Wb, size_t n4)
{
    size_t i = (size_t)blockIdx.x * blockDim.x + threadIdx.x;
    const size_t stride = (size_t)gridDim.x * blockDim.x;
    for (; i < n4; i += stride) {
        const i32x4 v = *(const i32x4*)(WP + i * 4);
        u32x4 wv;
        #pragma unroll
        for (int j = 0; j < 4; ++j) {
            const int b  = v[j];
            const int lo = (b << 28) >> 28;          // low nibble  -> even k
            const int hi = (b << 24) >> 28;          // high nibble -> odd  k
            const unsigned flo = __builtin_bit_cast(unsigned, (float)lo);
            const unsigned fhi = __builtin_bit_cast(unsigned, (float)hi);
            wv[j] = (fhi & 0xFFFF0000u) | (flo >> 16);  // exact bf16 for [-8,7]
        }
        *(u32x4*)(Wb + i * 8) = wv;
    }
}

// ---- main GEMM: pure bf16, global_load_lds both operands ----
__global__ __launch_bounds__(THREADS) void gemm_fast(
    const ushort* __restrict__ Xb,   // bf16 [M,K]
    const ushort* __restrict__ Wb,   // bf16 [N,K]
    const float*  __restrict__ WS,   // f32 [N]
    float*        __restrict__ OUT,  // f32 [M,N]
    int M, int N, int K)
{
    __shared__ ushort Alds[BM][BK];  // 16 KB
    __shared__ ushort Blds[BN][BK];  // 16 KB

    const int tid  = threadIdx.x;
    const int wave = tid >> 6;
    const int lane = tid & 63;
    const int m0 = blockIdx.y * BM;
    const int n0 = blockIdx.x * BN;
    const int wr = wave >> 1;
    const int wc = wave & 1;

    f32x4 acc[4][4] = {};

    const int a_row = lane >> 3;          // 0..7 within 8-row chunk
    const int a_col = (lane & 7) * 8;     // 8 bf16 = 16 B per lane

    for (int k0 = 0; k0 < K; k0 += BK) {
        #pragma unroll
        for (int c = 0; c < 4; ++c) {
            const int chunk = wave * 4 + c;          // 16 chunks x 8 rows
            const int row   = chunk * 8 + a_row;
            const ushort* srcA = Xb + (size_t)(m0 + row) * K + (k0 + a_col);
            __builtin_amdgcn_global_load_lds(
                (const __attribute__((address_space(1))) unsigned int*)srcA,
                (__attribute__((address_space(3))) unsigned int*)&Alds[chunk * 8][0],
                16, 0, 0);
            const ushort* srcB = Wb + (size_t)(n0 + row) * K + (k0 + a_col);
            __builtin_amdgcn_global_load_lds(
                (const __attribute__((address_space(1))) unsigned int*)srcB,
                (__attribute__((address_space(3))) unsigned int*)&Blds[chunk * 8][0],
                16, 0, 0);
        }
        __syncthreads();

        #pragma unroll
        for (int kk = 0; kk < 2; ++kk) {
            bf16x8 af[4], bfr[4];
            #pragma unroll
            for (int i = 0; i < 4; ++i)
                af[i] = *(const bf16x8*)&Alds[wr * 64 + i * 16 + (lane & 15)][kk * 32 + (lane >> 4) * 8];
            #pragma unroll
            for (int i = 0; i < 4; ++i)
                bfr[i] = *(const bf16x8*)&Blds[wc * 64 + i * 16 + (lane & 15)][kk * 32 + (lane >> 4) * 8];
            #pragma unroll
            for (int mi = 0; mi < 4; ++mi)
                #pragma unroll
                for (int ni = 0; ni < 4; ++ni)
                    acc[mi][ni] = __builtin_amdgcn_mfma_f32_16x16x32_bf16(
                        af[mi], bfr[ni], acc[mi][ni], 0, 0, 0);
        }
        __syncthreads();
    }

    // C/D layout: col = lane&15, row = (lane>>4)*4 + r  [m89/m91; r31-validated]
    const int col_l = lane & 15;
    const int row_l = (lane >> 4) * 4;
    #pragma unroll
    for (int ni = 0; ni < 4; ++ni) {
        const int col = n0 + wc * 64 + ni * 16 + col_l;
        const float s = WS[col];
        #pragma unroll
        for (int mi = 0; mi < 4; ++mi) {
            const int row = m0 + wr * 64 + mi * 16 + row_l;
            #pragma unroll
            for (int r = 0; r < 4; ++r)
                OUT[(size_t)(row + r) * N + col] = acc[mi][ni][r] * s;
        }
    }
}

// ---- fallback: r31's passing kernel (in-loop conversion) ----
__global__ __launch_bounds__(THREADS) void w4a16_gemm(
    const float* __restrict__ X, const int* __restrict__ WP,
    const float* __restrict__ WS, float* __restrict__ OUT,
    int M, int N, int K)
{
    __shared__ ushort Alds[BM][BK];
    __shared__ ushort Blds[BN][BK];

    const int tid  = threadIdx.x;
    const int wave = tid >> 6;
    const int lane = tid & 63;
    const int m0 = blockIdx.y * BM;
    const int n0 = blockIdx.x * BN;
    const int wr = wave >> 1;
    const int wc = wave & 1;

    f32x4 acc[4][4] = {};
    const int Khalf = K >> 1;

    for (int k0 = 0; k0 < K; k0 += BK) {
        #pragma unroll
        for (int i = 0; i < 4; ++i) {
            const int g   = i * THREADS + tid;
            const int row = g >> 3;
            const int col = (g & 7) * 8;
            const float* src = X + (size_t)(m0 + row) * K + (k0 + col);
            const f32x4 a0 = *(const f32x4*)(src);
            const f32x4 a1 = *(const f32x4*)(src + 4);
            u32x4 wv;
            wv[0] = ((uint)f2bf(a0[1]) << 16) | f2bf(a0[0]);
            wv[1] = ((uint)f2bf(a0[3]) << 16) | f2bf(a0[2]);
            wv[2] = ((uint)f2bf(a1[1]) << 16) | f2bf(a1[0]);
            wv[3] = ((uint)f2bf(a1[3]) << 16) | f2bf(a1[2]);
            *(u32x4*)&Alds[row][col] = wv;
        }
        #pragma unroll
        for (int i = 0; i < 4; ++i) {
            const int g   = i * THREADS + tid;
            const int row = g >> 3;
            const int c4  = (g & 7) * 4;
            const i32x4 v = *(const i32x4*)(WP + (size_t)(n0 + row) * Khalf + (k0 >> 1) + c4);
            u32x4 wv;
            #pragma unroll
            for (int j = 0; j < 4; ++j) {
                const int b  = v[j];
                const int lo = (b << 28) >> 28;
                const int hi = (b << 24) >> 28;
                const unsigned flo = __builtin_bit_cast(unsigned, (float)lo);
                const unsigned fhi = __builtin_bit_cast(unsigned, (float)hi);
                wv[j] = (fhi & 0xFFFF0000u) | (flo >> 16);
            }
            *(u32x4*)&Blds[row][c4 * 2] = wv;
        }
        __syncthreads();

        #pragma unroll
        for (int kk = 0; kk < 2; ++kk) {
            bf16x8 af[4], bfr[4];
            #pragma unroll
            for (int i = 0; i < 4; ++i)
                af[i] = *(const bf16x8*)&Alds[wr * 64 + i * 16 + (lane & 15)][kk * 32 + (lane >> 4) * 8];
            #pragma unroll
            for (int i = 0; i < 4; ++i)
                bfr[i] = *(const bf16x8*)&Blds[wc * 64 + i * 16 + (lane & 15)][kk * 32 + (lane >> 4) * 8];
            #pragma unroll
            for (int mi = 0; mi < 4; ++mi)
                #pragma unroll
                for (int ni = 0; ni < 4; ++ni)
                    acc[mi][ni] = __builtin_amdgcn_mfma_f32_16x16x32_bf16(
                        af[mi], bfr[ni], acc[mi][ni], 0, 0, 0);
        }
        __syncthreads();
    }

    const int col_l = lane & 15;
    const int row_l = (lane >> 4) * 4;
    #pragma unroll
    for (int ni = 0; ni < 4; ++ni) {
        const int col = n0 + wc * 64 + ni * 16 + col_l;
        const float s = WS[col];
        #pragma unroll
        for (int mi = 0; mi < 4; ++mi) {
            const int row = m0 + wr * 64 + mi * 16 + row_l;
            #pragma unroll
            for (int r = 0; r < 4; ++r)
                OUT[(size_t)(row + r) * N + col] = acc[mi][ni][r] * s;
        }
    }
}

extern "C" void kernel_launch(void* const* d_in, const int* in_sizes, int n_in,
                              void* d_out, int out_size, void* d_ws, size_t ws_size,
                              hipStream_t stream) {
    const float* X  = (const float*)d_in[0];
    const int*   WP = (const int*)d_in[1];
    const float* WS = (const float*)d_in[2];
    float*       OUT = (float*)d_out;

    const int N     = in_sizes[2];          // 11008
    const int Khalf = in_sizes[1] / N;      // 2048
    const int K     = Khalf * 2;            // 4096
    const int M     = in_sizes[0] / K;      // 8192

    const size_t xElems = (size_t)M * K;            // 33,554,432
    const size_t wElems = (size_t)N * K;            // 45,088,768
    const size_t need   = (xElems + wElems) * 2;    // 150 MB

    dim3 grid(N / BN, M / BM);              // (86, 64)
    if (ws_size >= need) {
        ushort* Xb = (ushort*)d_ws;
        ushort* Wb = Xb + xElems;
        cvt_x<<<2048, 256, 0, stream>>>(X, Xb, xElems / 8);
        cvt_w<<<2048, 256, 0, stream>>>(WP, Wb, (size_t)N * Khalf / 4);
        gemm_fast<<<grid, dim3(THREADS), 0, stream>>>(Xb, Wb, WS, OUT, M, N, K);
    } else {
        w4a16_gemm<<<grid, dim3(THREADS), 0, stream>>>(X, WP, WS, OUT, M, N, K);
    }
}

// Round 33
// 1133.837 us; speedup vs baseline: 1.2592x; 1.0784x over previous
//
#include <hip/hip_runtime.h>
#include <hip/hip_bf16.h>
#include <stdint.h>

#define BM 128
#define BN 128
#define BK 64
#define THREADS 256

typedef __attribute__((ext_vector_type(4))) float f32x4;
typedef __attribute__((ext_vector_type(8))) short bf16x8;
typedef __attribute__((ext_vector_type(4))) int i32x4;
typedef __attribute__((ext_vector_type(4))) unsigned int u32x4;

static __device__ __forceinline__ ushort f2bf(float f) {
    __hip_bfloat16 h = __float2bfloat16(f);   // RNE
    return *(const ushort*)&h;
}

// Round 33: T2 XOR-swizzle on the LDS tiles (rule #21 form: linear LDS dest
// for global_load_lds + INVERSE-swizzled global source + swizzled ds_read).
// r32 counters: SQ_LDS_BANK_CONFLICT 2.7e8 (= r31) — [128][64]-ushort tiles
// have 128-byte rows => fragment reads are 16-way bank conflicts (~440 us).
// Swizzle: LDS[r][c] holds global[c ^ 8*(r&7)] (ushort units); lane l stages
// from global col 8*((l&7)^(l>>3)); reads XOR col with 8*(lane&7).
// 16-way -> 2-way (free, m136). Numerics bit-identical to r31/r32.

// ---- pre-pass 1: X f32 -> bf16 ----
__global__ __launch_bounds__(256) void cvt_x(
    const float* __restrict__ X, ushort* __restrict__ Xb, size_t n8)
{
    size_t i = (size_t)blockIdx.x * blockDim.x + threadIdx.x;
    const size_t stride = (size_t)gridDim.x * blockDim.x;
    for (; i < n8; i += stride) {
        const f32x4 a0 = *(const f32x4*)(X + i * 8);
        const f32x4 a1 = *(const f32x4*)(X + i * 8 + 4);
        u32x4 wv;
        wv[0] = ((uint)f2bf(a0[1]) << 16) | f2bf(a0[0]);
        wv[1] = ((uint)f2bf(a0[3]) << 16) | f2bf(a0[2]);
        wv[2] = ((uint)f2bf(a1[1]) << 16) | f2bf(a1[0]);
        wv[3] = ((uint)f2bf(a1[3]) << 16) | f2bf(a1[2]);
        *(u32x4*)(Xb + i * 8) = wv;
    }
}

// ---- pre-pass 2: W packed-nibble -> bf16 [N,K] ----
__global__ __launch_bounds__(256) void cvt_w(
    const int* __restrict__ WP, ushort* __restrict__ Wb, size_t n4)
{
    size_t i = (size_t)blockIdx.x * blockDim.x + threadIdx.x;
    const size_t stride = (size_t)gridDim.x * blockDim.x;
    for (; i < n4; i += stride) {
        const i32x4 v = *(const i32x4*)(WP + i * 4);
        u32x4 wv;
        #pragma unroll
        for (int j = 0; j < 4; ++j) {
            const int b  = v[j];
            const int lo = (b << 28) >> 28;          // low nibble  -> even k
            const int hi = (b << 24) >> 28;          // high nibble -> odd  k
            const unsigned flo = __builtin_bit_cast(unsigned, (float)lo);
            const unsigned fhi = __builtin_bit_cast(unsigned, (float)hi);
            wv[j] = (fhi & 0xFFFF0000u) | (flo >> 16);  // exact bf16 for [-8,7]
        }
        *(u32x4*)(Wb + i * 8) = wv;
    }
}

// ---- main GEMM: pure bf16, global_load_lds + XOR-swizzled LDS ----
__global__ __launch_bounds__(THREADS) void gemm_swz(
    const ushort* __restrict__ Xb,   // bf16 [M,K]
    const ushort* __restrict__ Wb,   // bf16 [N,K]
    const float*  __restrict__ WS,   // f32 [N]
    float*        __restrict__ OUT,  // f32 [M,N]
    int M, int N, int K)
{
    __shared__ ushort Alds[BM][BK];  // 16 KB, swizzled contents
    __shared__ ushort Blds[BN][BK];  // 16 KB, swizzled contents

    const int tid  = threadIdx.x;
    const int wave = tid >> 6;
    const int lane = tid & 63;
    const int m0 = blockIdx.y * BM;
    const int n0 = blockIdx.x * BN;
    const int wr = wave >> 1;
    const int wc = wave & 1;

    f32x4 acc[4][4] = {};

    const int a_row  = lane >> 3;                         // 0..7 within chunk
    const int sw_col = 8 * ((lane & 7) ^ (lane >> 3));    // inverse-swizzled src col

    for (int k0 = 0; k0 < K; k0 += BK) {
        #pragma unroll
        for (int c = 0; c < 4; ++c) {
            const int chunk = wave * 4 + c;               // 16 chunks x 8 rows
            const int row   = chunk * 8 + a_row;
            const ushort* srcA = Xb + (size_t)(m0 + row) * K + (k0 + sw_col);
            __builtin_amdgcn_global_load_lds(
                (const __attribute__((address_space(1))) unsigned int*)srcA,
                (__attribute__((address_space(3))) unsigned int*)&Alds[chunk * 8][0],
                16, 0, 0);
            const ushort* srcB = Wb + (size_t)(n0 + row) * K + (k0 + sw_col);
            __builtin_amdgcn_global_load_lds(
                (const __attribute__((address_space(1))) unsigned int*)srcB,
                (__attribute__((address_space(3))) unsigned int*)&Blds[chunk * 8][0],
                16, 0, 0);
        }
        __syncthreads();

        const int swr = 8 * (lane & 7);                   // read-side XOR term
        #pragma unroll
        for (int kk = 0; kk < 2; ++kk) {
            const int colr = (kk * 32 + (lane >> 4) * 8) ^ swr;
            bf16x8 af[4], bfr[4];
            #pragma unroll
            for (int i = 0; i < 4; ++i)
                af[i] = *(const bf16x8*)&Alds[wr * 64 + i * 16 + (lane & 15)][colr];
            #pragma unroll
            for (int i = 0; i < 4; ++i)
                bfr[i] = *(const bf16x8*)&Blds[wc * 64 + i * 16 + (lane & 15)][colr];
            #pragma unroll
            for (int mi = 0; mi < 4; ++mi)
                #pragma unroll
                for (int ni = 0; ni < 4; ++ni)
                    acc[mi][ni] = __builtin_amdgcn_mfma_f32_16x16x32_bf16(
                        af[mi], bfr[ni], acc[mi][ni], 0, 0, 0);
        }
        __syncthreads();
    }

    // C/D layout: col = lane&15, row = (lane>>4)*4 + r  [m89/m91; r31-validated]
    const int col_l = lane & 15;
    const int row_l = (lane >> 4) * 4;
    #pragma unroll
    for (int ni = 0; ni < 4; ++ni) {
        const int col = n0 + wc * 64 + ni * 16 + col_l;
        const float s = WS[col];
        #pragma unroll
        for (int mi = 0; mi < 4; ++mi) {
            const int row = m0 + wr * 64 + mi * 16 + row_l;
            #pragma unroll
            for (int r = 0; r < 4; ++r)
                OUT[(size_t)(row + r) * N + col] = acc[mi][ni][r] * s;
        }
    }
}

// ---- fallback: r31's passing kernel (in-loop conversion, no ws needed) ----
__global__ __launch_bounds__(THREADS) void w4a16_gemm(
    const float* __restrict__ X, const int* __restrict__ WP,
    const float* __restrict__ WS, float* __restrict__ OUT,
    int M, int N, int K)
{
    __shared__ ushort Alds[BM][BK];
    __shared__ ushort Blds[BN][BK];

    const int tid  = threadIdx.x;
    const int wave = tid >> 6;
    const int lane = tid & 63;
    const int m0 = blockIdx.y * BM;
    const int n0 = blockIdx.x * BN;
    const int wr = wave >> 1;
    const int wc = wave & 1;

    f32x4 acc[4][4] = {};
    const int Khalf = K >> 1;

    for (int k0 = 0; k0 < K; k0 += BK) {
        #pragma unroll
        for (int i = 0; i < 4; ++i) {
            const int g   = i * THREADS + tid;
            const int row = g >> 3;
            const int col = (g & 7) * 8;
            const float* src = X + (size_t)(m0 + row) * K + (k0 + col);
            const f32x4 a0 = *(const f32x4*)(src);
            const f32x4 a1 = *(const f32x4*)(src + 4);
            u32x4 wv;
            wv[0] = ((uint)f2bf(a0[1]) << 16) | f2bf(a0[0]);
            wv[1] = ((uint)f2bf(a0[3]) << 16) | f2bf(a0[2]);
            wv[2] = ((uint)f2bf(a1[1]) << 16) | f2bf(a1[0]);
            wv[3] = ((uint)f2bf(a1[3]) << 16) | f2bf(a1[2]);
            *(u32x4*)&Alds[row][col] = wv;
        }
        #pragma unroll
        for (int i = 0; i < 4; ++i) {
            const int g   = i * THREADS + tid;
            const int row = g >> 3;
            const int c4  = (g & 7) * 4;
            const i32x4 v = *(const i32x4*)(WP + (size_t)(n0 + row) * Khalf + (k0 >> 1) + c4);
            u32x4 wv;
            #pragma unroll
            for (int j = 0; j < 4; ++j) {
                const int b  = v[j];
                const int lo = (b << 28) >> 28;
                const int hi = (b << 24) >> 28;
                const unsigned flo = __builtin_bit_cast(unsigned, (float)lo);
                const unsigned fhi = __builtin_bit_cast(unsigned, (float)hi);
                wv[j] = (fhi & 0xFFFF0000u) | (flo >> 16);
            }
            *(u32x4*)&Blds[row][c4 * 2] = wv;
        }
        __syncthreads();

        #pragma unroll
        for (int kk = 0; kk < 2; ++kk) {
            bf16x8 af[4], bfr[4];
            #pragma unroll
            for (int i = 0; i < 4; ++i)
                af[i] = *(const bf16x8*)&Alds[wr * 64 + i * 16 + (lane & 15)][kk * 32 + (lane >> 4) * 8];
            #pragma unroll
            for (int i = 0; i < 4; ++i)
                bfr[i] = *(const bf16x8*)&Blds[wc * 64 + i * 16 + (lane & 15)][kk * 32 + (lane >> 4) * 8];
            #pragma unroll
            for (int mi = 0; mi < 4; ++mi)
                #pragma unroll
                for (int ni = 0; ni < 4; ++ni)
                    acc[mi][ni] = __builtin_amdgcn_mfma_f32_16x16x32_bf16(
                        af[mi], bfr[ni], acc[mi][ni], 0, 0, 0);
        }
        __syncthreads();
    }

    const int col_l = lane & 15;
    const int row_l = (lane >> 4) * 4;
    #pragma unroll
    for (int ni = 0; ni < 4; ++ni) {
        const int col = n0 + wc * 64 + ni * 16 + col_l;
        const float s = WS[col];
        #pragma unroll
        for (int mi = 0; mi < 4; ++mi) {
            const int row = m0 + wr * 64 + mi * 16 + row_l;
            #pragma unroll
            for (int r = 0; r < 4; ++r)
                OUT[(size_t)(row + r) * N + col] = acc[mi][ni][r] * s;
        }
    }
}

extern "C" void kernel_launch(void* const* d_in, const int* in_sizes, int n_in,
                              void* d_out, int out_size, void* d_ws, size_t ws_size,
                              hipStream_t stream) {
    const float* X  = (const float*)d_in[0];
    const int*   WP = (const int*)d_in[1];
    const float* WS = (const float*)d_in[2];
    float*       OUT = (float*)d_out;

    const int N     = in_sizes[2];          // 11008
    const int Khalf = in_sizes[1] / N;      // 2048
    const int K     = Khalf * 2;            // 4096
    const int M     = in_sizes[0] / K;      // 8192

    const size_t xElems = (size_t)M * K;            // 33,554,432
    const size_t wElems = (size_t)N * K;            // 45,088,768
    const size_t need   = (xElems + wElems) * 2;    // 150 MB

    dim3 grid(N / BN, M / BM);              // (86, 64)
    if (ws_size >= need) {
        ushort* Xb = (ushort*)d_ws;
        ushort* Wb = Xb + xElems;
        cvt_x<<<2048, 256, 0, stream>>>(X, Xb, xElems / 8);
        cvt_w<<<2048, 256, 0, stream>>>(WP, Wb, (size_t)N * Khalf / 4);
        gemm_swz<<<grid, dim3(THREADS), 0, stream>>>(Xb, Wb, WS, OUT, M, N, K);
    } else {
        w4a16_gemm<<<grid, dim3(THREADS), 0, stream>>>(X, WP, WS, OUT, M, N, K);
    }
}